// Round 5
// baseline (1190.625 us; speedup 1.0000x reference)
//
#include <hip/hip_runtime.h>

typedef _Float16 half8 __attribute__((ext_vector_type(8)));
typedef float f32x4 __attribute__((ext_vector_type(4)));
typedef unsigned int u32x4 __attribute__((ext_vector_type(4)));

#define SC_AGENT __HIP_MEMORY_SCOPE_AGENT

// Problem: B=16, T=64, L=64, H=256. K=2H=512, N=4H=1024.
//
// Tag-in-word protocol, round 5:
//   word = [h0 f16 | h1 f16 | tag32 ], tag = (epoch<<8)|t. epoch bumped by a
//   pre-kernel each launch => stale L2 lines from prior launches never match.
//
//   DUAL publish per word (same address, same data):
//     (a) plain global_store_dwordx2  -> updates home (write-back) L2:
//         same-XCD consumers detect at L2 latency (~0.15us)
//     (b) global_store_dwordx2 sc0 sc1 -> IC (coherent truth, cross-XCD)
//   Consumer polls sc0 (L1-bypass, L2-served) rounds 0-2, sc0+sc1 (IC) every
//   4th round. Placement heuristic (XCD-affine remap) affects ONLY which tier
//   fires; sc1 tier bounds detection regardless (G16-safe).
//
//   Critical path per step = ONE cheap poll RT + work. Backpressure moved
//   off-path (tid0, overlapped with epilogue/barrier; prog monotone => stale
//   sc0 reads are conservative-safe). No coarse gate.
//
// ws: prog[256] u32 @0 (logical idx l*4+r); epoch u32 @4096; Hw @64KB (2MB).
constexpr size_t OFF_PROG  = 0;
constexpr size_t OFF_EPOCH = 4096;
constexpr size_t OFF_H     = 65536;
constexpr size_t SLOT_STRIDE = (size_t)64 * 16 * 128;  // words per slot

__device__ __forceinline__ size_t Widx(int l, int b, int wi) {
  return ((size_t)l * 16 + b) * 128 + wi;
}
__device__ __forceinline__ float sigm(float v) { return 1.0f / (1.0f + __expf(-v)); }
__device__ __forceinline__ float tanh_(float v) { return 1.0f - 2.0f / (__expf(2.0f * v) + 1.0f); }

// Batched poll loads: async; MUST be followed by s_waitcnt vmcnt(0) +
// sched_barrier(0) before reading dst (rule #18).
#define POLL_L2(dst, base, OFS)                                          \
  asm volatile("global_load_dwordx2 %0, %1, off offset:" #OFS " sc0"     \
               : "=v"(dst) : "v"(base))
#define POLL_IC(dst, base, OFS)                                          \
  asm volatile("global_load_dwordx2 %0, %1, off offset:" #OFS " sc0 sc1" \
               : "=v"(dst) : "v"(base))

#define ISSUE_ALL(M)                          \
  if (pend & 0x0001u) M(wv_[0],  sp0, 0);     \
  if (pend & 0x0002u) M(wv_[1],  sp0, 8);     \
  if (pend & 0x0004u) M(wv_[2],  sp0, 16);    \
  if (pend & 0x0008u) M(wv_[3],  sp0, 24);    \
  if (pend & 0x0010u) M(wv_[4],  sp1, 0);     \
  if (pend & 0x0020u) M(wv_[5],  sp1, 8);     \
  if (pend & 0x0040u) M(wv_[6],  sp1, 16);    \
  if (pend & 0x0080u) M(wv_[7],  sp1, 24);    \
  if (pend & 0x0100u) M(wv_[8],  sp2, 0);     \
  if (pend & 0x0200u) M(wv_[9],  sp2, 8);     \
  if (pend & 0x0400u) M(wv_[10], sp2, 16);    \
  if (pend & 0x0800u) M(wv_[11], sp2, 24);    \
  if (pend & 0x1000u) M(wv_[12], sp3, 0);     \
  if (pend & 0x2000u) M(wv_[13], sp3, 8);     \
  if (pend & 0x4000u) M(wv_[14], sp3, 16);    \
  if (pend & 0x8000u) M(wv_[15], sp3, 24);

// ---------------- epoch bump: 1 thread, before init_ws (stream-ordered) ----
__global__ void bump_epoch(char* ws) {
  unsigned* ep = (unsigned*)(ws + OFF_EPOCH);
  unsigned v = __hip_atomic_load(ep, __ATOMIC_RELAXED, SC_AGENT);
  __hip_atomic_store(ep, v + 1, __ATOMIC_RELAXED, SC_AGENT);
}

// ---------------- init: prog=(ep<<8)-1, slot0 tag=0, slot1 tag=(ep<<8)|0xFF ----
// Plain stores are fine: kernel-end writeback makes them agent-visible.
__global__ void init_ws(const float* __restrict__ init_state, char* ws) {
  unsigned* prog = (unsigned*)(ws + OFF_PROG);
  unsigned long long* Hw = (unsigned long long*)(ws + OFF_H);
  const unsigned ep = __hip_atomic_load((unsigned*)(ws + OFF_EPOCH),
                                        __ATOMIC_RELAXED, SC_AGENT);
  const unsigned long long tagInit = ((unsigned long long)((ep << 8) | 0xFFu)) << 32;
  const int tid = blockIdx.x * 256 + threadIdx.x;  // 65536 threads
  if (tid < 256) prog[tid] = (ep << 8) - 1u;
  for (int e = tid; e < 64 * 16 * 128; e += 65536) {
    const int wi = e & 127, b = (e >> 7) & 15, l = e >> 11;
    Hw[Widx(l, b, wi)] = 0ULL;  // slot0: tag 0 never matches (ep>=1)
    union { _Float16 f; unsigned short s; } h0, h1;
    h0.f = (_Float16)init_state[((l * 2 + 1) * 16 + b) * 256 + 2 * wi];
    h1.f = (_Float16)init_state[((l * 2 + 1) * 16 + b) * 256 + 2 * wi + 1];
    Hw[SLOT_STRIDE + Widx(l, b, wi)] =
        (unsigned long long)h0.s | ((unsigned long long)h1.s << 16) | tagInit;
  }
}

// ---------------- main: 256 WGs; XCD-affine (l,r): layers 8k..8k+7 on XCD k ----
__global__ __launch_bounds__(256, 1) void lstm_mfma(
    const float* __restrict__ x, const float* __restrict__ init_state,
    const float* __restrict__ W, const float* __restrict__ bias,
    float* __restrict__ out, char* ws) {
  unsigned* prog = (unsigned*)(ws + OFF_PROG);
  unsigned long long* Hw = (unsigned long long*)(ws + OFF_H);

  const int tid = threadIdx.x;
  const int wg = blockIdx.x;
  const int l = ((wg & 7) << 3) | (wg >> 5);  // XCD(wg)=wg%8=l>>3
  const int r = (wg >> 3) & 3;
  const int wv = tid >> 6, lane = tid & 63;

  const unsigned epb = __hip_atomic_load((unsigned*)(ws + OFF_EPOCH),
                                         __ATOMIC_RELAXED, SC_AGENT) << 8;

  __shared__ alignas(16) _Float16 aLds[16 * 64 * 8];  // A-frags, 16 KB
  __shared__ alignas(16) float zLds[16 * 260];        // z transpose, 16.6 KB
  __shared__ unsigned short hLds[16 * 64];            // nh f16 bits, 2 KB

  // ---- W slice -> registers (unchanged) ----
  half8 wreg[64];
#pragma unroll
  for (int q = 0; q < 4; ++q) {
    const int nl = (wv * 4 + q) * 16 + (lane & 15);
    const int col = (nl & 3) * 256 + r * 64 + (nl >> 2);
#pragma unroll
    for (int kb = 0; kb < 16; ++kb) {
      const int k0 = kb * 32 + (lane >> 4) * 8;
      const float* src = W + (size_t)k0 * 1024 + col;
      half8 hv;
#pragma unroll
      for (int jj = 0; jj < 8; ++jj) hv[jj] = (_Float16)src[(size_t)jj * 1024];
      wreg[q * 16 + kb] = hv;
    }
  }

  // ---- per-thread epilogue identity ----
  const int hu = tid & 63, b4 = tid >> 6;
  const int gu = r * 64 + hu;
  float creg[4];
#pragma unroll
  for (int bb = 0; bb < 4; ++bb)
    creg[bb] = init_state[((l * 2 + 0) * 16 + (b4 * 4 + bb)) * 256 + gu];
  const float bi_ = bias[0 * 256 + gu], bj_ = bias[1 * 256 + gu];
  const float bf_ = bias[2 * 256 + gu], bo_ = bias[3 * 256 + gu];

  // ---- staging entry invariants ----
  int kbA[4], lnA[4];
  size_t wbase[4];
#pragma unroll
  for (int i = 0; i < 4; ++i) {
    const int e = i * 256 + tid, kb = e >> 6, ln = e & 63;
    const int m = ln & 15, k0 = kb * 32 + (ln >> 4) * 8;
    kbA[i] = kb; lnA[i] = ln;
    wbase[i] = (i < 2) ? (l > 0 ? Widx(l - 1, m, k0 >> 1) : 0)
                       : Widx(l, m, (k0 - 256) >> 1);
  }

  unsigned* const bpBase = (l < 63) ? &prog[(l + 1) * 4] : prog;

  for (int t = 0; t < 64; ++t) {
    const int slotCur = t & 1, slotPrev = (t + 1) & 1;
    const unsigned expIn = epb | (unsigned)t;                          // h(l-1,t)
    const unsigned expOwn = (t > 0) ? (epb | (unsigned)(t - 1)) : (epb | 0xFFu);

    if (l == 0) {
#pragma unroll
      for (int i = 0; i < 2; ++i) {
        const int kb = kbA[i], ln = lnA[i];
        const int m = ln & 15, k0 = kb * 32 + (ln >> 4) * 8;
        const float* xs = x + ((size_t)m * 64 + t) * 256 + k0;
        half8 hv;
#pragma unroll
        for (int jj = 0; jj < 8; ++jj) hv[jj] = (_Float16)xs[jj];
        *(half8*)&aLds[(size_t)(kb * 64 + ln) * 8] = hv;
      }
    }

    // ---- poll+stage: tiered (L2 3/4 rounds, IC every 4th), single vmcnt ----
    unsigned pend = (l == 0) ? 0xFF00u : 0xFFFFu;
    int round = 0;
    while (pend) {
      unsigned long long wv_[16];
      const unsigned long long* sp0 = Hw + (slotCur ? SLOT_STRIDE : 0) + wbase[0];
      const unsigned long long* sp1 = Hw + (slotCur ? SLOT_STRIDE : 0) + wbase[1];
      const unsigned long long* sp2 = Hw + (slotPrev ? SLOT_STRIDE : 0) + wbase[2];
      const unsigned long long* sp3 = Hw + (slotPrev ? SLOT_STRIDE : 0) + wbase[3];
      if ((round & 3) == 3) { ISSUE_ALL(POLL_IC) } else { ISSUE_ALL(POLL_L2) }
      asm volatile("s_waitcnt vmcnt(0)" ::: "memory");
      __builtin_amdgcn_sched_barrier(0);
#pragma unroll
      for (int i = 0; i < 4; ++i) {
        unsigned* dp = (unsigned*)&aLds[(size_t)(kbA[i] * 64 + lnA[i]) * 8];
        const unsigned exp_ = (i < 2) ? expIn : expOwn;
#pragma unroll
        for (int j = 0; j < 4; ++j) {
          const int b_ = i * 4 + j;
          if ((pend >> b_) & 1u) {
            const unsigned long long wd = wv_[b_];
            if ((unsigned)(wd >> 32) == exp_) {
              dp[j] = (unsigned)wd;  // low 32b = two f16 h values
              pend &= ~(1u << b_);
            }
          }
        }
      }
      if (pend) {
        if (++round > 500000) break;  // hang guard: fail visibly, not dead
        if ((round & 15) == 15) __builtin_amdgcn_s_sleep(1);
      }
    }
    __syncthreads();
    // prog publish: dual store (plain -> home L2; sc1 -> IC truth)
    if (tid == 0) {
      unsigned pv = epb | (unsigned)t;
      unsigned* pp = &prog[l * 4 + r];
      asm volatile("global_store_dword %0, %1, off" :: "v"(pp), "v"(pv) : "memory");
      asm volatile("global_store_dword %0, %1, off sc0 sc1" :: "v"(pp), "v"(pv) : "memory");
    }

    // ---- GEMM (unchanged) ----
    f32x4 acc[4] = {{0.f, 0.f, 0.f, 0.f}, {0.f, 0.f, 0.f, 0.f},
                    {0.f, 0.f, 0.f, 0.f}, {0.f, 0.f, 0.f, 0.f}};
#pragma unroll
    for (int kb = 0; kb < 16; ++kb) {
      half8 a = *(const half8*)&aLds[(kb * 64 + lane) * 8];
#pragma unroll
      for (int q = 0; q < 4; ++q)
        acc[q] = __builtin_amdgcn_mfma_f32_16x16x32_f16(a, wreg[q * 16 + kb], acc[q], 0, 0, 0);
    }

    // ---- z -> LDS transpose (unchanged) ----
#pragma unroll
    for (int q = 0; q < 4; ++q) {
      const int nl = (wv * 4 + q) * 16 + (lane & 15);
      const int m0 = (lane >> 4) * 4;
#pragma unroll
      for (int rg = 0; rg < 4; ++rg) zLds[(m0 + rg) * 260 + nl] = acc[q][rg];
    }
    __syncthreads();

    // ---- LSTM epilogue ----
#pragma unroll
    for (int bb = 0; bb < 4; ++bb) {
      const int b = b4 * 4 + bb;
      f32x4 zg = *(const f32x4*)&zLds[b * 260 + hu * 4];  // (i,j,f,o)
      const float iv = zg[0] + bi_, jv = zg[1] + bj_;
      const float fv = zg[2] + bf_, ov = zg[3] + bo_;
      const float nc = sigm(fv + 1.0f) * creg[bb] + sigm(iv) * tanh_(jv);
      const float nh = sigm(ov) * tanh_(nc);
      creg[bb] = nc;
      union { _Float16 f; unsigned short s; } cv;
      cv.f = (_Float16)nh;
      hLds[b * 64 + hu] = cv.s;
      if (l == 63) out[((size_t)b * 64 + t) * 256 + gu] = nh;
    }

    // ---- backpressure: tid0, overlapped with siblings' epilogue+barrier.
    // prog monotone => stale sc0 under-reports => conservative-safe.
    if (tid == 0 && l < 63 && t >= 2) {
      const unsigned need = epb | (unsigned)(t - 2);
      int g = 0;
      while (true) {
        u32x4 pv;
        if (g & 1) {
          asm volatile("global_load_dwordx4 %0, %1, off sc0 sc1" : "=v"(pv) : "v"(bpBase));
        } else {
          asm volatile("global_load_dwordx4 %0, %1, off sc0" : "=v"(pv) : "v"(bpBase));
        }
        asm volatile("s_waitcnt vmcnt(0)" ::: "memory");
        __builtin_amdgcn_sched_barrier(0);
        if (pv[0] >= need && pv[1] >= need && pv[2] >= need && pv[3] >= need) break;
        __builtin_amdgcn_s_sleep(1);
        if (++g > 500000) break;  // hang guard
      }
    }
    __syncthreads();

    // ---- publish: dual store per word (plain -> L2; sc0 sc1 -> IC) ----
    {
      const int b = tid >> 4, lw0 = (tid & 15) * 2;
#pragma unroll
      for (int q = 0; q < 2; ++q) {
        const int lw = lw0 + q, u0 = 2 * lw;
        unsigned lo = (unsigned)hLds[b * 64 + u0] | ((unsigned)hLds[b * 64 + u0 + 1] << 16);
        unsigned long long wd =
            (unsigned long long)lo | ((unsigned long long)expIn << 32);
        unsigned long long* dst =
            Hw + (slotCur ? SLOT_STRIDE : 0) + Widx(l, b, r * 32 + lw);
        asm volatile("global_store_dwordx2 %0, %1, off" :: "v"(dst), "v"(wd) : "memory");
        asm volatile("global_store_dwordx2 %0, %1, off sc0 sc1" :: "v"(dst), "v"(wd) : "memory");
      }
    }
    // no trailing barrier: next iter's staging barrier orders aLds/hLds reuse
  }
}

extern "C" void kernel_launch(void* const* d_in, const int* in_sizes, int n_in,
                              void* d_out, int out_size, void* d_ws,
                              size_t ws_size, hipStream_t stream) {
  const float* x          = (const float*)d_in[0];
  const float* init_state = (const float*)d_in[1];
  const float* W          = (const float*)d_in[2];
  const float* bias       = (const float*)d_in[3];
  float* out = (float*)d_out;
  char* ws   = (char*)d_ws;

  bump_epoch<<<1, 1, 0, stream>>>(ws);
  init_ws<<<256, 256, 0, stream>>>(init_state, ws);
  lstm_mfma<<<256, 256, 0, stream>>>(x, init_state, W, bias, out, ws);
}

// Round 6
// 677.139 us; speedup vs baseline: 1.7583x; 1.7583x over previous
//
#include <hip/hip_runtime.h>

typedef _Float16 half8 __attribute__((ext_vector_type(8)));
typedef float f32x4 __attribute__((ext_vector_type(4)));
typedef unsigned int u32;
typedef unsigned int u32x4 __attribute__((ext_vector_type(4)));

#define SC_AGENT __HIP_MEMORY_SCOPE_AGENT

// Problem: B=16, T=64, L=64, H=256. K=2H=512, N=4H=1024.
//
// Round 6: minimize producer tail (publish ASAP after GEMM) + 2-barrier step.
//   h published as 4B words [h f16 | tag16], tag16 = (ep<<7)|tt, tt = t (0..63)
//   for real steps, 127 for the h(l,-1) init (never collides with real t).
//   All h/prog traffic is sc0 sc1 (IC truth) -- placement-independent, G16-safe.
//   Single store per word (R5's dual plain+sc store caused L2/IC ping-pong).
//
//   Step: [gate (cached)] -> poll -> barrier -> GEMM -> barrier ->
//         shfl-transpose -> epilogue -> publish from registers.
//   The 4x4 lane-group butterfly (xor 1, then xor 2) gives new[k][rg] =
//   old[rg][k]: each lane ends holding all 4 gates (i,j,f,o) of one
//   (unit, batch) pair per q-tile -- no zLds, no hLds, no extra barriers.
//
//   Fill-phase flood control: cached min(prog[l-1]) gate with s_sleep(4);
//   zero cost in steady state (cached), stops ~200 filling WGs from
//   hammering IC. Backpressure: cached, tid0, one dwordx4.
//
// ws: prog[256] u32 @0 (idx l*4+r); epoch u32 @4096; Hw4 @64KB:
//     u32[2 slots][64 l][16 b][256 u] = 2 MB.
constexpr size_t OFF_PROG  = 0;
constexpr size_t OFF_EPOCH = 4096;
constexpr size_t OFF_H     = 65536;
constexpr size_t S4 = (size_t)64 * 16 * 256;  // u32 words per slot

__device__ __forceinline__ float sigm(float v) { return 1.0f / (1.0f + __expf(-v)); }
__device__ __forceinline__ float tanh_(float v) { return 1.0f - 2.0f / (__expf(2.0f * v) + 1.0f); }

// Async IC loads: MUST be followed by s_waitcnt vmcnt(0) + sched_barrier(0)
// before reading dst (rule #18).
#define GLD4(dst, base, OFS)                                                  \
  asm volatile("global_load_dwordx4 %0, %1, off offset:" #OFS " sc0 sc1"      \
               : "=v"(dst) : "v"(base))

// ---------------- epoch bump: ep cycles 1..511 (tag16 epoch field, 9 bits) ----
__global__ void bump_epoch(char* ws) {
  u32* ep = (u32*)(ws + OFF_EPOCH);
  u32 v = __hip_atomic_load(ep, __ATOMIC_RELAXED, SC_AGENT);
  u32 n = (v + 1) & 0x1FFu;
  if (n == 0) n = 1;
  __hip_atomic_store(ep, n, __ATOMIC_RELAXED, SC_AGENT);
}

// ---------------- init: prog=epb-1, slot0 words tag 0 (never matches, ep>=1),
// slot1 = h(l,-1) with tag epb|127 ----------------
__global__ void init_ws(const float* __restrict__ init_state, char* ws) {
  u32* prog = (u32*)(ws + OFF_PROG);
  u32* Hw4 = (u32*)(ws + OFF_H);
  const u32 ep = __hip_atomic_load((u32*)(ws + OFF_EPOCH), __ATOMIC_RELAXED, SC_AGENT);
  const u32 epb = (ep & 0x1FFu) << 7;  // ep in [1,511] -> epb >= 128
  const int tid = blockIdx.x * 256 + threadIdx.x;  // 65536 threads
  if (tid < 256) prog[tid] = epb - 1u;  // < epb|t for all t
  const u32 tagInit = (epb | 127u) << 16;
  for (int e = tid; e < 64 * 16 * 256; e += 65536) {
    const int u = e & 255, b = (e >> 8) & 15, l = e >> 12;
    const size_t idx = ((size_t)l * 16 + b) * 256 + u;
    Hw4[idx] = 0u;  // slot0: tag 0, never matches
    union { _Float16 f; unsigned short s; } hv;
    hv.f = (_Float16)init_state[((l * 2 + 1) * 16 + b) * 256 + u];
    Hw4[S4 + idx] = (u32)hv.s | tagInit;
  }
}

// ---------------- main: 256 WGs = (layer l = wg>>2, slice r = wg&3) ----------------
__global__ __launch_bounds__(256, 1) void lstm_mfma(
    const float* __restrict__ x, const float* __restrict__ init_state,
    const float* __restrict__ W, const float* __restrict__ bias,
    float* __restrict__ out, char* ws) {
  u32* prog = (u32*)(ws + OFF_PROG);
  u32* Hw4 = (u32*)(ws + OFF_H);

  const int tid = threadIdx.x;
  const int wg = blockIdx.x;
  const int l = wg >> 2, r = wg & 3;
  const int wv = tid >> 6, lane = tid & 63;

  const u32 epb = (__hip_atomic_load((u32*)(ws + OFF_EPOCH), __ATOMIC_RELAXED,
                                     SC_AGENT) & 0x1FFu) << 7;

  __shared__ alignas(16) _Float16 aLds[16 * 64 * 8];  // A-frags: [kb][lane][8], 16 KB

  // ---- W slice -> registers (unchanged layout) ----
  half8 wreg[64];
#pragma unroll
  for (int q = 0; q < 4; ++q) {
    const int nl = (wv * 4 + q) * 16 + (lane & 15);
    const int col = (nl & 3) * 256 + r * 64 + (nl >> 2);
#pragma unroll
    for (int kb = 0; kb < 16; ++kb) {
      const int k0 = kb * 32 + (lane >> 4) * 8;
      const float* src = W + (size_t)k0 * 1024 + col;
      half8 hv;
#pragma unroll
      for (int jj = 0; jj < 8; ++jj) hv[jj] = (_Float16)src[(size_t)jj * 1024];
      wreg[q * 16 + kb] = hv;
    }
  }

  // ---- per-thread epilogue identity (post-butterfly): per q-tile this thread
  // owns (unit u_q, batch m_own), all 4 gates in-lane.
  const int m_own = (lane >> 4) * 4 + (lane & 3);
  int gu_q[4];
  float creg[4], bI[4], bJ[4], bF[4], bO[4];
#pragma unroll
  for (int q = 0; q < 4; ++q) {
    const int u_q = (wv * 4 + q) * 4 + ((lane & 15) >> 2);  // unit in slice
    gu_q[q] = r * 64 + u_q;
    creg[q] = init_state[((l * 2 + 0) * 16 + m_own) * 256 + gu_q[q]];
    bI[q] = bias[0 * 256 + gu_q[q]];
    bJ[q] = bias[1 * 256 + gu_q[q]];
    bF[q] = bias[2 * 256 + gu_q[q]];
    bO[q] = bias[3 * 256 + gu_q[q]];
  }

  // ---- staging geometry: entry i (i<2: k-low = h(l-1,t) or x; i>=2: k-high =
  // own h(l,t-1)); granule g = 4 units = one dwordx4. bit b = i*2+g. ----
  const int m = lane & 15;
  const int ksub = (lane >> 4) * 8;  // k-offset within a kb tile

  u32 plCache = 0, bpCache = 0;  // cached prog gates (monotone within launch)

  for (int t = 0; t < 64; ++t) {
    const int slotCur = t & 1, slotPrev = (t + 1) & 1;
    const u32 expIn = epb | (u32)t;                               // h(l-1,t)
    const u32 expOwn = (t > 0) ? (epb | (u32)(t - 1)) : (epb | 127u);

    // ---- l==0: x staging (entries 0,1) ----
    if (l == 0) {
#pragma unroll
      for (int i = 0; i < 2; ++i) {
        const int kb = i * 4 + wv;
        const int k0 = kb * 32 + ksub;
        const float* xs = x + ((size_t)m * 64 + t) * 256 + k0;
        half8 hv;
#pragma unroll
        for (int jj = 0; jj < 8; ++jj) hv[jj] = (_Float16)xs[jj];
        *(half8*)&aLds[(size_t)(kb * 64 + lane) * 8] = hv;
      }
    }

    // ---- fill-phase gate: cached min(prog[l-1][0..3]) >= epb|t ----
    if (l > 0 && plCache < (epb | (u32)t)) {
      u32* pb = &prog[(l - 1) * 4];
      int g = 0;
      while (true) {
        u32x4 pv;
        GLD4(pv, pb, 0);
        asm volatile("s_waitcnt vmcnt(0)" ::: "memory");
        __builtin_amdgcn_sched_barrier(0);
        u32 mn = pv[0] < pv[1] ? pv[0] : pv[1];
        mn = mn < pv[2] ? mn : pv[2];
        mn = mn < pv[3] ? mn : pv[3];
        plCache = mn;
        if (mn >= (epb | (u32)t)) break;
        __builtin_amdgcn_s_sleep(4);
        if (++g > 800000) break;  // hang guard: fail visibly, not dead
      }
    }

    // ---- backpressure (publish of t overwrites h(l,t-2)): cached, tid0 ----
    if (tid == 0 && l < 63 && t >= 2 && bpCache < (epb | (u32)(t - 2))) {
      u32* pb = &prog[(l + 1) * 4];
      int g = 0;
      while (true) {
        u32x4 pv;
        GLD4(pv, pb, 0);
        asm volatile("s_waitcnt vmcnt(0)" ::: "memory");
        __builtin_amdgcn_sched_barrier(0);
        u32 mn = pv[0] < pv[1] ? pv[0] : pv[1];
        mn = mn < pv[2] ? mn : pv[2];
        mn = mn < pv[3] ? mn : pv[3];
        bpCache = mn;
        if (mn >= (epb | (u32)(t - 2))) break;
        __builtin_amdgcn_s_sleep(2);
        if (++g > 800000) break;  // hang guard
      }
    }

    // ---- data poll: batched dwordx4 IC loads, one vmcnt, tag-check ----
    unsigned pend = (l == 0) ? 0xF0u : 0xFFu;  // bit = i*2+g
    const u32* pLow = Hw4 + (slotCur ? S4 : 0) +
                      (((size_t)(l > 0 ? l - 1 : 0) * 16 + m) * 256) + wv * 32 + ksub;
    const u32* pHigh = Hw4 + (slotPrev ? S4 : 0) +
                       (((size_t)l * 16 + m) * 256) + wv * 32 + ksub;
    int round = 0;
    while (pend) {
      u32x4 gv[8];
      if (pend & 0x01u) GLD4(gv[0], pLow, 0);    // i=0 g=0
      if (pend & 0x02u) GLD4(gv[1], pLow, 16);   // i=0 g=1
      if (pend & 0x04u) GLD4(gv[2], pLow, 512);  // i=1 g=0
      if (pend & 0x08u) GLD4(gv[3], pLow, 528);  // i=1 g=1
      if (pend & 0x10u) GLD4(gv[4], pHigh, 0);   // i=2 g=0
      if (pend & 0x20u) GLD4(gv[5], pHigh, 16);  // i=2 g=1
      if (pend & 0x40u) GLD4(gv[6], pHigh, 512); // i=3 g=0
      if (pend & 0x80u) GLD4(gv[7], pHigh, 528); // i=3 g=1
      asm volatile("s_waitcnt vmcnt(0)" ::: "memory");
      __builtin_amdgcn_sched_barrier(0);
#pragma unroll
      for (int b = 0; b < 8; ++b) {
        if ((pend >> b) & 1u) {
          const u32 exp_ = (b < 4) ? expIn : expOwn;
          const u32x4 v = gv[b];
          if ((v[0] >> 16) == exp_ && (v[1] >> 16) == exp_ &&
              (v[2] >> 16) == exp_ && (v[3] >> 16) == exp_) {
            const int kb = (b >> 1) * 4 + wv;
            u32* dp = (u32*)&aLds[(size_t)(kb * 64 + lane) * 8 + (b & 1) * 4];
            dp[0] = (v[0] & 0xFFFFu) | (v[1] << 16);
            dp[1] = (v[2] & 0xFFFFu) | (v[3] << 16);
            pend &= ~(1u << b);
          }
        }
      }
      if (pend) {
        if (++round > 500000) break;  // hang guard
        if (round > 32 && (round & 3) == 0) __builtin_amdgcn_s_sleep(1);
      }
    }
    __syncthreads();
    if (tid == 0)
      __hip_atomic_store(&prog[l * 4 + r], epb | (u32)t, __ATOMIC_RELAXED, SC_AGENT);

    // ---- GEMM: z[16 x 256slice] = A[16x512] * Wslice[512x256] ----
    f32x4 acc[4] = {{0.f, 0.f, 0.f, 0.f}, {0.f, 0.f, 0.f, 0.f},
                    {0.f, 0.f, 0.f, 0.f}, {0.f, 0.f, 0.f, 0.f}};
#pragma unroll
    for (int kb = 0; kb < 16; ++kb) {
      half8 a = *(const half8*)&aLds[(kb * 64 + lane) * 8];
#pragma unroll
      for (int q = 0; q < 4; ++q)
        acc[q] = __builtin_amdgcn_mfma_f32_16x16x32_f16(a, wreg[q * 16 + kb], acc[q], 0, 0, 0);
    }
    __syncthreads();  // aLds reads done -> next iter may overwrite

    // ---- 4x4 lane-group butterfly transpose + epilogue + IMMEDIATE publish ----
    // acc[q][rg] = z[m=(lane>>4)*4+rg][gate=lane&3, unit=u_q]. After butterfly
    // (xor1 then xor2): v[g] = gate g for (u_q, m_own). Publish per q ASAP.
#pragma unroll
    for (int q = 0; q < 4; ++q) {
      float v0 = acc[q][0], v1 = acc[q][1], v2 = acc[q][2], v3 = acc[q][3];
      // step 1 (xor 1): new[rg] = ((rg^lane)&1) ? shfl_xor(old[rg^1],1) : old[rg]
      float e0 = __shfl_xor(v1, 1, 64), e1 = __shfl_xor(v0, 1, 64);
      float e2 = __shfl_xor(v3, 1, 64), e3 = __shfl_xor(v2, 1, 64);
      const bool o1 = (lane & 1);
      float m0 = o1 ? e0 : v0, m1 = o1 ? v1 : e1;
      float m2 = o1 ? e2 : v2, m3 = o1 ? v3 : e3;
      // step 2 (xor 2): new[rg] = ((rg^lane)&2) ? shfl_xor(mid[rg^2],2) : mid[rg]
      float f0 = __shfl_xor(m2, 2, 64), f1 = __shfl_xor(m3, 2, 64);
      float f2 = __shfl_xor(m0, 2, 64), f3 = __shfl_xor(m1, 2, 64);
      const bool o2 = (lane & 2);
      float gI = o2 ? f0 : m0, gJ = o2 ? f1 : m1;
      float gF = o2 ? m2 : f2, gO = o2 ? m3 : f3;

      const float iv = gI + bI[q], jv = gJ + bJ[q];
      const float fv = gF + bF[q], ov = gO + bO[q];
      const float nc = sigm(fv + 1.0f) * creg[q] + sigm(iv) * tanh_(jv);
      const float nh = sigm(ov) * tanh_(nc);
      creg[q] = nc;
      union { _Float16 f; unsigned short s; } cv;
      cv.f = (_Float16)nh;
      const size_t idx = (slotCur ? S4 : 0) +
                         ((size_t)l * 16 + m_own) * 256 + gu_q[q];
      __hip_atomic_store(Hw4 + idx, (u32)cv.s | (expIn << 16),
                         __ATOMIC_RELAXED, SC_AGENT);
      if (l == 63) out[((size_t)m_own * 64 + t) * 256 + gu_q[q]] = nh;
    }
    // no trailing barrier: post-GEMM barrier already isolates aLds epochs
  }
}

extern "C" void kernel_launch(void* const* d_in, const int* in_sizes, int n_in,
                              void* d_out, int out_size, void* d_ws,
                              size_t ws_size, hipStream_t stream) {
  const float* x          = (const float*)d_in[0];
  const float* init_state = (const float*)d_in[1];
  const float* W          = (const float*)d_in[2];
  const float* bias       = (const float*)d_in[3];
  float* out = (float*)d_out;
  char* ws   = (char*)d_ws;

  bump_epoch<<<1, 1, 0, stream>>>(ws);
  init_ws<<<256, 256, 0, stream>>>(init_state, ws);
  lstm_mfma<<<256, 256, 0, stream>>>(x, init_state, W, bias, out, ws);
}